// Round 1
// baseline (1284.264 us; speedup 1.0000x reference)
//
#include <hip/hip_runtime.h>
#include <hip/hip_bf16.h>

#define D_IN   4096
#define D_OUT  4096
#define NTOK   8192
#define SEQ    2048
#define ER     64        // E*R
#define SCALING 2.0f

typedef float        f32x4  __attribute__((ext_vector_type(4)));
typedef unsigned int u32x4  __attribute__((ext_vector_type(4)));
typedef unsigned int u32x2  __attribute__((ext_vector_type(2)));
typedef short        s16x8  __attribute__((ext_vector_type(8)));
typedef __bf16       bf16x8 __attribute__((ext_vector_type(8)));

__device__ inline unsigned f2bf1(float f){
    unsigned u = __builtin_bit_cast(unsigned, f);
    return (u + 0x7fffu + ((u >> 16) & 1u)) >> 16;
}
__device__ inline float bf2f(unsigned b){ return __builtin_bit_cast(float, b << 16); }
__device__ inline unsigned pack2(float a, float b){ return f2bf1(a) | (f2bf1(b) << 16); }

__device__ inline f32x4 mfma_bf16(s16x8 a, s16x8 b, f32x4 c){
    return __builtin_amdgcn_mfma_f32_16x16x32_bf16(
        __builtin_bit_cast(bf16x8, a), __builtin_bit_cast(bf16x8, b), c, 0, 0, 0);
}

// ---------------------------------------------------------------------------
// K1: fused router + LoRA-A projection.
//   c[t][e*16+r] = gate[t][e] * SCALING * dot(x[t], lora_A[e][r])
// 32-token tile (aligns with SPLIT=32 -> router choice uniform per block).
// N = 80 cols: 64 er + 4 router logits + 12 zero pad.
// ---------------------------------------------------------------------------
__global__ __launch_bounds__(256) void lora_c_kernel(
    const float* __restrict__ x,
    const float* __restrict__ wr_img, const float* __restrict__ br_img,
    const float* __restrict__ wr_txt, const float* __restrict__ br_txt,
    const float* __restrict__ lA,
    float* __restrict__ c_ws)
{
    __shared__ short xs[32][32];
    __shared__ short bs[80][32];
    __shared__ float lg[32][4];

    const int tid  = threadIdx.x;
    const int lane = tid & 63;
    const int wid  = tid >> 6;
    const int t0   = blockIdx.x * 32;
    const bool img = ((t0 % SEQ) == 0);
    const float* wr = img ? wr_img : wr_txt;
    const float* br = img ? br_img : br_txt;

    const int xr = tid >> 3;          // 0..31
    const int xk = (tid & 7) * 4;     // 0..28

    f32x4 acc0  = {0.f,0.f,0.f,0.f}, acc1  = {0.f,0.f,0.f,0.f};
    f32x4 accR0 = {0.f,0.f,0.f,0.f}, accR1 = {0.f,0.f,0.f,0.f};

    f32x4 rx, rb0, rb1, rb2;
    rx  = *(const f32x4*)(x  + (size_t)(t0 + xr) * D_IN + xk);
    rb0 = *(const f32x4*)(lA + (size_t)xr        * D_IN + xk);
    rb1 = *(const f32x4*)(lA + (size_t)(xr + 32) * D_IN + xk);
    rb2 = (f32x4){0.f,0.f,0.f,0.f};
    if (xr < 4) rb2 = *(const f32x4*)(wr + (size_t)xr * D_IN + xk);

    for (int ks = 0; ks < 128; ++ks){
        __syncthreads();
        *(u32x2*)&xs[xr][xk]      = (u32x2){pack2(rx[0],rx[1]),   pack2(rx[2],rx[3])};
        *(u32x2*)&bs[xr][xk]      = (u32x2){pack2(rb0[0],rb0[1]), pack2(rb0[2],rb0[3])};
        *(u32x2*)&bs[xr + 32][xk] = (u32x2){pack2(rb1[0],rb1[1]), pack2(rb1[2],rb1[3])};
        if (xr < 16)
            *(u32x2*)&bs[xr + 64][xk] = (u32x2){pack2(rb2[0],rb2[1]), pack2(rb2[2],rb2[3])};
        __syncthreads();
        if (ks < 127){
            const int ko = (ks + 1) * 32;
            rx  = *(const f32x4*)(x  + (size_t)(t0 + xr) * D_IN + ko + xk);
            rb0 = *(const f32x4*)(lA + (size_t)xr        * D_IN + ko + xk);
            rb1 = *(const f32x4*)(lA + (size_t)(xr + 32) * D_IN + ko + xk);
            rb2 = (f32x4){0.f,0.f,0.f,0.f};
            if (xr < 4) rb2 = *(const f32x4*)(wr + (size_t)xr * D_IN + ko + xk);
        }
        const int fr = lane & 15, fq = lane >> 4;
        s16x8 a0 = *(const s16x8*)&xs[fr][fq * 8];
        s16x8 a1 = *(const s16x8*)&xs[16 + fr][fq * 8];
        s16x8 b0 = *(const s16x8*)&bs[wid * 16 + fr][fq * 8];
        acc0 = mfma_bf16(a0, b0, acc0);
        acc1 = mfma_bf16(a1, b0, acc1);
        if (wid == 0){
            s16x8 bR = *(const s16x8*)&bs[64 + fr][fq * 8];
            accR0 = mfma_bf16(a0, bR, accR0);
            accR1 = mfma_bf16(a1, bR, accR1);
        }
    }

    __syncthreads();
    const int fr = lane & 15, fq = lane >> 4;
    if (wid == 0 && fr < 4){
        #pragma unroll
        for (int r = 0; r < 4; ++r){
            lg[fq * 4 + r][fr]      = accR0[r] + br[fr];
            lg[16 + fq * 4 + r][fr] = accR1[r] + br[fr];
        }
    }
    __syncthreads();
    if (tid < 32){
        float l0 = lg[tid][0], l1 = lg[tid][1], l2 = lg[tid][2], l3 = lg[tid][3];
        float mx = fmaxf(fmaxf(l0, l1), fmaxf(l2, l3));
        float e0 = expf(l0 - mx), e1 = expf(l1 - mx), e2 = expf(l2 - mx), e3 = expf(l3 - mx);
        float inv = SCALING / (e0 + e1 + e2 + e3);
        lg[tid][0] = e0 * inv; lg[tid][1] = e1 * inv;
        lg[tid][2] = e2 * inv; lg[tid][3] = e3 * inv;
    }
    __syncthreads();
    #pragma unroll
    for (int r = 0; r < 4; ++r){
        const int row0 = fq * 4 + r;
        c_ws[(size_t)(t0 + row0)      * ER + wid * 16 + fr] = acc0[r] * lg[row0][wid];
        c_ws[(size_t)(t0 + row0 + 16) * ER + wid * 16 + fr] = acc1[r] * lg[row0 + 16][wid];
    }
}

// ---------------------------------------------------------------------------
// K2: main GEMM  out = x @ w^T (3-product bf16 hi/lo split, ~fp32 accurate)
//     + epilogue: bias + LoRA second projection via MFMA (c @ Bt, K=64).
// 128x128 tile, BK=32, 4 waves of 64x64.
// LDS planar layout [k-slot(4)][row(128)] x 16B  -> conflict-free frag reads.
// ---------------------------------------------------------------------------
#define PSTRIDE 2064                       // 128*16 + 16B pad
#define ABUF    (4 * PSTRIDE)              // 8256 B per operand-half

__device__ inline void cvt_write16(char* H, char* L, int off, f32x4 a, f32x4 b){
    float f[8] = {a[0],a[1],a[2],a[3], b[0],b[1],b[2],b[3]};
    unsigned h[8], l[8];
    #pragma unroll
    for (int i = 0; i < 8; ++i){
        h[i] = f2bf1(f[i]);
        l[i] = f2bf1(f[i] - bf2f(h[i]));
    }
    *(u32x4*)(H + off) = (u32x4){h[0]|(h[1]<<16), h[2]|(h[3]<<16), h[4]|(h[5]<<16), h[6]|(h[7]<<16)};
    *(u32x4*)(L + off) = (u32x4){l[0]|(l[1]<<16), l[2]|(l[3]<<16), l[4]|(l[5]<<16), l[6]|(l[7]<<16)};
}

__global__ __launch_bounds__(256, 2) void main_gemm_kernel(
    const float* __restrict__ x, const float* __restrict__ w,
    const float* __restrict__ bias, const float* __restrict__ lB,
    const float* __restrict__ c_ws, float* __restrict__ out)
{
    __shared__ __align__(16) char smem[4 * ABUF];   // 33 KB; epilogue reuses it
    char* Ah = smem;
    char* Al = smem + ABUF;
    char* Bh = smem + 2 * ABUF;
    char* Bl = smem + 3 * ABUF;

    const int tid  = threadIdx.x;
    const int lane = tid & 63;
    const int wid  = tid >> 6;
    const int wr   = wid >> 1, wc = wid & 1;

    const int bid = blockIdx.x;
    const int swz = ((bid & 7) << 8) | (bid >> 3);   // XCD swizzle (2048 % 8 == 0)
    const int tm  = swz & 63, tn = swz >> 6;
    const int m0  = tm * 128, n0 = tn * 128;

    // staging: thread -> rows (sr, sr+64), k-slot ss (8 floats each)
    const int sr = tid >> 2;
    const int ss = tid & 3;
    const float* xa = x + (size_t)(m0 + sr)      * D_IN + ss * 8;
    const float* xb = x + (size_t)(m0 + sr + 64) * D_IN + ss * 8;
    const float* wa = w + (size_t)(n0 + sr)      * D_IN + ss * 8;
    const float* wb = w + (size_t)(n0 + sr + 64) * D_IN + ss * 8;
    const int off0 = ss * PSTRIDE + sr * 16;
    const int off1 = ss * PSTRIDE + (sr + 64) * 16;

    f32x4 r0a, r0b, r1a, r1b, r2a, r2b, r3a, r3b;
    r0a = *(const f32x4*)(xa);     r0b = *(const f32x4*)(xa + 4);
    r1a = *(const f32x4*)(xb);     r1b = *(const f32x4*)(xb + 4);
    r2a = *(const f32x4*)(wa);     r2b = *(const f32x4*)(wa + 4);
    r3a = *(const f32x4*)(wb);     r3b = *(const f32x4*)(wb + 4);

    f32x4 acc[4][4];
    #pragma unroll
    for (int m = 0; m < 4; ++m)
        #pragma unroll
        for (int n = 0; n < 4; ++n) acc[m][n] = (f32x4){0.f,0.f,0.f,0.f};

    const int fr = lane & 15, fq = lane >> 4;

    for (int ks = 0; ks < 128; ++ks){
        __syncthreads();
        cvt_write16(Ah, Al, off0, r0a, r0b);
        cvt_write16(Ah, Al, off1, r1a, r1b);
        cvt_write16(Bh, Bl, off0, r2a, r2b);
        cvt_write16(Bh, Bl, off1, r3a, r3b);
        __syncthreads();
        if (ks < 127){
            const size_t ko = (size_t)(ks + 1) * 32;
            r0a = *(const f32x4*)(xa + ko);     r0b = *(const f32x4*)(xa + ko + 4);
            r1a = *(const f32x4*)(xb + ko);     r1b = *(const f32x4*)(xb + ko + 4);
            r2a = *(const f32x4*)(wa + ko);     r2b = *(const f32x4*)(wa + ko + 4);
            r3a = *(const f32x4*)(wb + ko);     r3b = *(const f32x4*)(wb + ko + 4);
        }
        s16x8 bh[4], bl[4];
        #pragma unroll
        for (int n = 0; n < 4; ++n){
            const int col = wc * 64 + n * 16 + fr;
            const int o   = fq * PSTRIDE + col * 16;
            bh[n] = *(const s16x8*)(Bh + o);
            bl[n] = *(const s16x8*)(Bl + o);
        }
        #pragma unroll
        for (int m = 0; m < 4; ++m){
            const int row = wr * 64 + m * 16 + fr;
            const int o   = fq * PSTRIDE + row * 16;
            s16x8 ah = *(const s16x8*)(Ah + o);
            s16x8 al = *(const s16x8*)(Al + o);
            #pragma unroll
            for (int n = 0; n < 4; ++n){
                acc[m][n] = mfma_bf16(ah, bh[n], acc[m][n]);
                acc[m][n] = mfma_bf16(ah, bl[n], acc[m][n]);
                acc[m][n] = mfma_bf16(al, bh[n], acc[m][n]);
            }
        }
    }

    // -------- epilogue: stage c[128][64] and Bt[128][64] as bf16, 2 MFMAs/frag
    __syncthreads();
    {
        const int row = tid >> 1, half = tid & 1;
        const float* cs = c_ws + (size_t)(m0 + row) * ER + half * 32;
        short* cd = (short*)smem + row * 64 + half * 32;
        #pragma unroll
        for (int i = 0; i < 8; ++i){
            f32x4 v = *(const f32x4*)(cs + i * 4);
            *(u32x2*)(cd + i * 4) = (u32x2){pack2(v[0],v[1]), pack2(v[2],v[3])};
        }
        short* bd = (short*)(smem + 16384) + row * 64 + half * 32;
        #pragma unroll
        for (int j = 0; j < 2; ++j){
            const float* bsrc = lB + (size_t)(half * 2 + j) * D_OUT * 16 + (size_t)(n0 + row) * 16;
            #pragma unroll
            for (int i = 0; i < 4; ++i){
                f32x4 v = *(const f32x4*)(bsrc + i * 4);
                *(u32x2*)(bd + j * 16 + i * 4) = (u32x2){pack2(v[0],v[1]), pack2(v[2],v[3])};
            }
        }
    }
    __syncthreads();
    {
        const short* cl  = (const short*)smem;
        const short* btl = (const short*)(smem + 16384);
        #pragma unroll
        for (int kk = 0; kk < 2; ++kk){
            s16x8 bfr[4];
            #pragma unroll
            for (int n = 0; n < 4; ++n)
                bfr[n] = *(const s16x8*)(btl + (wc * 64 + n * 16 + fr) * 64 + kk * 32 + fq * 8);
            #pragma unroll
            for (int m = 0; m < 4; ++m){
                s16x8 af = *(const s16x8*)(cl + (wr * 64 + m * 16 + fr) * 64 + kk * 32 + fq * 8);
                #pragma unroll
                for (int n = 0; n < 4; ++n)
                    acc[m][n] = mfma_bf16(af, bfr[n], acc[m][n]);
            }
        }
    }
    // -------- bias + store
    #pragma unroll
    for (int n = 0; n < 4; ++n){
        const int col = n0 + wc * 64 + n * 16 + fr;
        const float bb = bias[col];
        #pragma unroll
        for (int m = 0; m < 4; ++m){
            const int row = m0 + wr * 64 + m * 16 + fq * 4;
            #pragma unroll
            for (int r = 0; r < 4; ++r)
                out[(size_t)(row + r) * D_OUT + col] = acc[m][n][r] + bb;
        }
    }
}

extern "C" void kernel_launch(void* const* d_in, const int* in_sizes, int n_in,
                              void* d_out, int out_size, void* d_ws, size_t ws_size,
                              hipStream_t stream)
{
    const float* x      = (const float*)d_in[0];
    const float* w_base = (const float*)d_in[1];
    const float* b_base = (const float*)d_in[2];
    const float* wr_img = (const float*)d_in[3];
    const float* br_img = (const float*)d_in[4];
    const float* wr_txt = (const float*)d_in[5];
    const float* br_txt = (const float*)d_in[6];
    const float* lA     = (const float*)d_in[7];
    const float* lB     = (const float*)d_in[8];
    float* out  = (float*)d_out;
    float* c_ws = (float*)d_ws;                 // 8192*64 floats = 2 MB

    lora_c_kernel<<<dim3(NTOK / 32), dim3(256), 0, stream>>>(
        x, wr_img, br_img, wr_txt, br_txt, lA, c_ws);
    main_gemm_kernel<<<dim3(2048), dim3(256), 0, stream>>>(
        x, w_base, b_base, lB, c_ws, out);
}

// Round 2
// 806.556 us; speedup vs baseline: 1.5923x; 1.5923x over previous
//
#include <hip/hip_runtime.h>
#include <hip/hip_bf16.h>

#define D_IN   4096
#define D_OUT  4096
#define NTOK   8192
#define SEQ    2048
#define ER     64
#define NKT    64            // K-tiles (4096/64) in main GEMM

typedef float        f32x4  __attribute__((ext_vector_type(4)));
typedef unsigned int u32x2  __attribute__((ext_vector_type(2)));
typedef short        s16x8  __attribute__((ext_vector_type(8)));
typedef __bf16       bf16x8 __attribute__((ext_vector_type(8)));
typedef _Float16     f16x8  __attribute__((ext_vector_type(8)));

// ---------------- bf16 helpers (lora_c path, numerics identical to R1) ------
__device__ inline unsigned f2bf1(float f){
    unsigned u = __builtin_bit_cast(unsigned, f);
    return (u + 0x7fffu + ((u >> 16) & 1u)) >> 16;
}
__device__ inline unsigned pack2(float a, float b){ return f2bf1(a) | (f2bf1(b) << 16); }
__device__ inline f32x4 mfma_bf16(s16x8 a, s16x8 b, f32x4 c){
    return __builtin_amdgcn_mfma_f32_16x16x32_bf16(
        __builtin_bit_cast(bf16x8, a), __builtin_bit_cast(bf16x8, b), c, 0, 0, 0);
}
// ---------------- fp16 helpers (main GEMM) ----------------------------------
__device__ inline f32x4 mfma16(s16x8 a, s16x8 b, f32x4 c){
    return __builtin_amdgcn_mfma_f32_16x16x32_f16(
        __builtin_bit_cast(f16x8, a), __builtin_bit_cast(f16x8, b), c, 0, 0, 0);
}

// ---------------------------------------------------------------------------
// K0: pre-convert.  xh = fp16(x);  wh/wl = fp16 hi/lo of (w*64).
// (x64 pre-scale keeps the wl plane in fp16 normal range; epilogue does /64.)
// ---------------------------------------------------------------------------
__global__ __launch_bounds__(256) void convert_kernel(
    const float* __restrict__ x, const float* __restrict__ w,
    _Float16* __restrict__ xh, _Float16* __restrict__ wh, _Float16* __restrict__ wl)
{
    const int b = blockIdx.x;
    if (b < 16384){
        size_t i = ((size_t)b * 256 + threadIdx.x) * 8;
        f32x4 a = *(const f32x4*)(x + i);
        f32x4 c = *(const f32x4*)(x + i + 4);
        f16x8 h;
        #pragma unroll
        for (int j = 0; j < 4; ++j){ h[j] = (_Float16)a[j]; h[4+j] = (_Float16)c[j]; }
        *(f16x8*)(xh + i) = h;
    } else {
        size_t i = ((size_t)(b - 16384) * 256 + threadIdx.x) * 8;
        f32x4 a = *(const f32x4*)(w + i);
        f32x4 c = *(const f32x4*)(w + i + 4);
        f16x8 h, l;
        #pragma unroll
        for (int j = 0; j < 4; ++j){
            float s0 = a[j] * 64.0f, s1 = c[j] * 64.0f;
            h[j]   = (_Float16)s0;  l[j]   = (_Float16)(s0 - (float)h[j]);
            h[4+j] = (_Float16)s1;  l[4+j] = (_Float16)(s1 - (float)h[4+j]);
        }
        *(f16x8*)(wh + i) = h;
        *(f16x8*)(wl + i) = l;
    }
}

// ---------------------------------------------------------------------------
// K1: fused router + LoRA-A projection (bf16, numerics identical to R1;
// restructured: K-chunk 128 -> 32 iterations, padded LDS rows (272B) to kill
// the 8-way bank conflicts).
// ---------------------------------------------------------------------------
__global__ __launch_bounds__(256) void lora_c_kernel(
    const float* __restrict__ x,
    const float* __restrict__ wr_img, const float* __restrict__ br_img,
    const float* __restrict__ wr_txt, const float* __restrict__ br_txt,
    const float* __restrict__ lA,
    float* __restrict__ c_ws)
{
    __shared__ short xs[32][136];
    __shared__ short bs[80][136];
    __shared__ float lg[32][4];

    const int tid  = threadIdx.x;
    const int lane = tid & 63;
    const int wid  = tid >> 6;
    const int t0   = blockIdx.x * 32;
    const bool img = ((t0 % SEQ) == 0);
    const float* wrr = img ? wr_img : wr_txt;
    const float* br  = img ? br_img : br_txt;

    // zero router pad rows 68..79 (read by router MFMA, never written)
    for (int idx = tid; idx < 816; idx += 256)
        ((unsigned*)&bs[68][0])[idx] = 0u;

    const int xr = tid >> 3;
    const int xc = (tid & 7) * 4;
    const int lr = tid >> 2;
    const int lc = (tid & 3) * 4;
    const int rrow = tid >> 5;          // valid for tid<128 -> 0..3
    const int rcol = (tid & 31) * 4;

    f32x4 rx[4], rb[8], rv = {0.f,0.f,0.f,0.f};
    #pragma unroll
    for (int j = 0; j < 4; ++j) rx[j] = *(const f32x4*)(x  + (size_t)(t0 + xr) * D_IN + xc + j*32);
    #pragma unroll
    for (int j = 0; j < 8; ++j) rb[j] = *(const f32x4*)(lA + (size_t)lr       * D_IN + lc + j*16);
    if (tid < 128) rv = *(const f32x4*)(wrr + (size_t)rrow * D_IN + rcol);

    f32x4 acc0={0,0,0,0}, acc1={0,0,0,0}, accR0={0,0,0,0}, accR1={0,0,0,0};
    const int fr = lane & 15, fq = lane >> 4;

    for (int ks = 0; ks < 32; ++ks){
        __syncthreads();
        #pragma unroll
        for (int j = 0; j < 4; ++j)
            *(u32x2*)&xs[xr][xc + j*32] = (u32x2){pack2(rx[j][0],rx[j][1]), pack2(rx[j][2],rx[j][3])};
        #pragma unroll
        for (int j = 0; j < 8; ++j)
            *(u32x2*)&bs[lr][lc + j*16] = (u32x2){pack2(rb[j][0],rb[j][1]), pack2(rb[j][2],rb[j][3])};
        if (tid < 128)
            *(u32x2*)&bs[64 + rrow][rcol] = (u32x2){pack2(rv[0],rv[1]), pack2(rv[2],rv[3])};
        __syncthreads();
        if (ks < 31){
            const int ko = (ks + 1) * 128;
            #pragma unroll
            for (int j = 0; j < 4; ++j) rx[j] = *(const f32x4*)(x  + (size_t)(t0 + xr) * D_IN + ko + xc + j*32);
            #pragma unroll
            for (int j = 0; j < 8; ++j) rb[j] = *(const f32x4*)(lA + (size_t)lr       * D_IN + ko + lc + j*16);
            if (tid < 128) rv = *(const f32x4*)(wrr + (size_t)rrow * D_IN + ko + rcol);
        }
        #pragma unroll
        for (int kc = 0; kc < 4; ++kc){
            s16x8 a0 = *(const s16x8*)&xs[fr][kc*32 + fq*8];
            s16x8 a1 = *(const s16x8*)&xs[16 + fr][kc*32 + fq*8];
            s16x8 b0 = *(const s16x8*)&bs[wid*16 + fr][kc*32 + fq*8];
            acc0 = mfma_bf16(a0, b0, acc0);
            acc1 = mfma_bf16(a1, b0, acc1);
            if (wid == 0){
                s16x8 bR = *(const s16x8*)&bs[64 + fr][kc*32 + fq*8];
                accR0 = mfma_bf16(a0, bR, accR0);
                accR1 = mfma_bf16(a1, bR, accR1);
            }
        }
    }

    __syncthreads();
    if (wid == 0 && fr < 4){
        #pragma unroll
        for (int r = 0; r < 4; ++r){
            lg[fq*4 + r][fr]      = accR0[r] + br[fr];
            lg[16 + fq*4 + r][fr] = accR1[r] + br[fr];
        }
    }
    __syncthreads();
    if (tid < 32){
        float l0 = lg[tid][0], l1 = lg[tid][1], l2 = lg[tid][2], l3 = lg[tid][3];
        float mx = fmaxf(fmaxf(l0, l1), fmaxf(l2, l3));
        float e0 = expf(l0 - mx), e1 = expf(l1 - mx), e2 = expf(l2 - mx), e3 = expf(l3 - mx);
        float inv = 2.0f / (e0 + e1 + e2 + e3);
        lg[tid][0] = e0 * inv; lg[tid][1] = e1 * inv;
        lg[tid][2] = e2 * inv; lg[tid][3] = e3 * inv;
    }
    __syncthreads();
    #pragma unroll
    for (int r = 0; r < 4; ++r){
        const int row0 = fq*4 + r;
        c_ws[(size_t)(t0 + row0)      * ER + wid*16 + fr] = acc0[r] * lg[row0][wid];
        c_ws[(size_t)(t0 + row0 + 16) * ER + wid*16 + fr] = acc1[r] * lg[row0 + 16][wid];
    }
}

// ---------------------------------------------------------------------------
// K2: main GEMM, m201-style 8-phase schedule.
// BM=256 (x, single fp16), BN=128 (w as hi+lo fp16 planes, pre-scaled x64),
// BK=64, 512 thr / 8 waves (4x2), wave tile 64x64, LDS 128 KiB double-buffer.
// XOR swizzle: 16B chunk c of row -> c ^ (row&7); staged via pre-swizzled
// global source + linear global_load_lds dest (rule 21).
// Epilogue: acc/64 + LoRA second projection (c @ Bt via MFMA) + bias.
// ---------------------------------------------------------------------------
#define BHOFF  32768
#define BLOFF  49152
#define BUFSZ  65536

__device__ inline void gload16(const void* g, void* l){
    __builtin_amdgcn_global_load_lds(
        (const __attribute__((address_space(1))) unsigned*)g,
        (__attribute__((address_space(3))) unsigned*)l, 16, 0, 0);
}
__device__ inline void stage_half_tile(const _Float16* gbase, char* lds, int tid){
    #pragma unroll
    for (int j = 0; j < 2; ++j){
        int q   = j*512 + tid;
        int row = q >> 3;
        int c7  = (q & 7) ^ (row & 7);
        gload16(gbase + (size_t)row * D_IN + c7*8, lds + q*16);
    }
}
__device__ inline s16x8 ldsfrag(const char* region, int row, int kc, int fq){
    int ch = ((kc << 2) + fq) ^ (row & 7);
    return *(const s16x8*)(region + row*128 + ch*16);
}

__global__ __launch_bounds__(512, 2) void main_gemm_kernel(
    const _Float16* __restrict__ xh, const _Float16* __restrict__ wh,
    const _Float16* __restrict__ wl,
    const float* __restrict__ bias, const float* __restrict__ lB,
    const float* __restrict__ c_ws, float* __restrict__ out)
{
    __shared__ __align__(16) char smem[2 * BUFSZ];

    const int tid  = threadIdx.x;
    const int lane = tid & 63;
    const int wid  = tid >> 6;
    const int wr   = wid >> 1;           // 0..3
    const int wc   = wid & 1;            // 0..1
    const int fr   = lane & 15, fq = lane >> 4;

    const int bid = blockIdx.x;
    const int swz = (bid & 7) * 128 + (bid >> 3);   // XCD swizzle, 1024%8==0
    const int mt  = swz & 31, nt = swz >> 5;
    const int m0  = mt * 256, n0 = nt * 128;

    const _Float16* gA0 = xh + (size_t)m0 * D_IN;
    const _Float16* gA1 = xh + (size_t)(m0 + 128) * D_IN;
    const _Float16* gBh = wh + (size_t)n0 * D_IN;
    const _Float16* gBl = wl + (size_t)n0 * D_IN;

    // prologue: stage T0.{A0,A1,Bh,Bl}, T1.{A0,A1,Bh}  (14 loads/thread)
    stage_half_tile(gA0,      smem + 0,              tid);
    stage_half_tile(gA1,      smem + 16384,          tid);
    stage_half_tile(gBh,      smem + BHOFF,          tid);
    stage_half_tile(gBl,      smem + BLOFF,          tid);
    stage_half_tile(gA0 + 64, smem + BUFSZ + 0,      tid);
    stage_half_tile(gA1 + 64, smem + BUFSZ + 16384,  tid);
    stage_half_tile(gBh + 64, smem + BUFSZ + BHOFF,  tid);
    asm volatile("s_waitcnt vmcnt(4)" ::: "memory");
    __builtin_amdgcn_s_barrier();

    f32x4 acc[4][4];
    #pragma unroll
    for (int mi = 0; mi < 4; ++mi)
        #pragma unroll
        for (int n = 0; n < 4; ++n) acc[mi][n] = (f32x4){0.f,0.f,0.f,0.f};

    for (int it = 0; it < 32; ++it){
        const bool pred = (it < 31);
        #pragma unroll
        for (int hf = 0; hf < 2; ++hf){
            char* buf = smem + hf * BUFSZ;
            s16x8 af[4][2];
            #pragma unroll
            for (int p = 0; p < 4; ++p){
                const int plane = p >> 1, nq = p & 1;
                // --- ds reads for this phase ---
                if (p == 0){
                    #pragma unroll
                    for (int mi = 0; mi < 4; ++mi)
                        #pragma unroll
                        for (int kc = 0; kc < 2; ++kc)
                            af[mi][kc] = ldsfrag(buf, wr*64 + mi*16 + fr, kc, fq);
                }
                s16x8 bf[2][2];
                const char* breg = buf + (plane ? BLOFF : BHOFF);
                #pragma unroll
                for (int nn = 0; nn < 2; ++nn)
                    #pragma unroll
                    for (int kc = 0; kc < 2; ++kc)
                        bf[nn][kc] = ldsfrag(breg, wc*64 + (nq*2 + nn)*16 + fr, kc, fq);
                // --- stage one half-tile (slot schedule; see header note) ---
                if (hf == 0){
                    if      (p == 0)         stage_half_tile(gBl + (size_t)(2*it+1)*64, smem + BUFSZ + BLOFF, tid);
                    else if (p == 1){ if (pred) stage_half_tile(gA0 + (size_t)(2*it+2)*64, smem + 0,          tid); }
                    else if (p == 2){ if (pred) stage_half_tile(gA1 + (size_t)(2*it+2)*64, smem + 16384,      tid); }
                    else            { if (pred) stage_half_tile(gBh + (size_t)(2*it+2)*64, smem + BHOFF,      tid); }
                } else {
                    if      (p == 0){ if (pred) stage_half_tile(gBl + (size_t)(2*it+2)*64, smem + BLOFF,          tid); }
                    else if (p == 1){ if (pred) stage_half_tile(gA0 + (size_t)(2*it+3)*64, smem + BUFSZ + 0,      tid); }
                    else if (p == 2){ if (pred) stage_half_tile(gA1 + (size_t)(2*it+3)*64, smem + BUFSZ + 16384,  tid); }
                    else            { if (pred) stage_half_tile(gBh + (size_t)(2*it+3)*64, smem + BUFSZ + BHOFF,  tid); }
                }
                __builtin_amdgcn_s_barrier();
                asm volatile("s_waitcnt lgkmcnt(0)" ::: "memory");
                __builtin_amdgcn_s_setprio(1);
                #pragma unroll
                for (int mi = 0; mi < 4; ++mi)
                    #pragma unroll
                    for (int nn = 0; nn < 2; ++nn)
                        #pragma unroll
                        for (int kc = 0; kc < 2; ++kc){
                            const int n = nq*2 + nn;
                            acc[mi][n] = mfma16(af[mi][kc], bf[nn][kc], acc[mi][n]);
                        }
                __builtin_amdgcn_s_setprio(0);
                if (p == 3){
                    if (hf == 0){
                        if (pred) asm volatile("s_waitcnt vmcnt(6)" ::: "memory");
                        else      asm volatile("s_waitcnt vmcnt(0)" ::: "memory");
                    } else {
                        asm volatile("s_waitcnt vmcnt(6)" ::: "memory");
                    }
                }
                __builtin_amdgcn_s_barrier();
            }
        }
    }

    // ---- epilogue: rescale (w was x64), LoRA second projection, bias, store
    #pragma unroll
    for (int mi = 0; mi < 4; ++mi)
        #pragma unroll
        for (int n = 0; n < 4; ++n) acc[mi][n] *= 0.015625f;

    // stage c[256][64] fp16 at smem[0..32K), Bt[128][64] fp16 at smem[32K..48K)
    #pragma unroll
    for (int k2 = 0; k2 < 4; ++k2){
        int q = tid + k2*512;              // 0..2047
        int row = q >> 3, cc = q & 7;
        const float* cs = c_ws + (size_t)(m0 + row) * ER + cc*8;
        f32x4 v0 = *(const f32x4*)cs;
        f32x4 v1 = *(const f32x4*)(cs + 4);
        f16x8 h;
        #pragma unroll
        for (int j = 0; j < 4; ++j){ h[j] = (_Float16)v0[j]; h[4+j] = (_Float16)v1[j]; }
        *(s16x8*)(smem + row*128 + (cc ^ (row & 7))*16) = __builtin_bit_cast(s16x8, h);
    }
    #pragma unroll
    for (int k2 = 0; k2 < 2; ++k2){
        int q = tid + k2*512;              // 0..1023
        int row = q >> 3, cc = q & 7;
        int e = cc >> 1, r0 = (cc & 1) * 8;
        const float* bsrc = lB + (size_t)e * D_OUT * 16 + (size_t)(n0 + row) * 16 + r0;
        f32x4 v0 = *(const f32x4*)bsrc;
        f32x4 v1 = *(const f32x4*)(bsrc + 4);
        f16x8 h;
        #pragma unroll
        for (int j = 0; j < 4; ++j){ h[j] = (_Float16)v0[j]; h[4+j] = (_Float16)v1[j]; }
        *(s16x8*)(smem + BHOFF + row*128 + (cc ^ (row & 7))*16) = __builtin_bit_cast(s16x8, h);
    }
    __syncthreads();

    #pragma unroll
    for (int kc = 0; kc < 2; ++kc){
        s16x8 btf[4];
        #pragma unroll
        for (int n = 0; n < 4; ++n)
            btf[n] = ldsfrag(smem + BHOFF, wc*64 + n*16 + fr, kc, fq);
        #pragma unroll
        for (int mi = 0; mi < 4; ++mi){
            s16x8 cf = ldsfrag(smem, wr*64 + mi*16 + fr, kc, fq);
            #pragma unroll
            for (int n = 0; n < 4; ++n)
                acc[mi][n] = mfma16(cf, btf[n], acc[mi][n]);
        }
    }

    #pragma unroll
    for (int n = 0; n < 4; ++n){
        const int col = n0 + wc*64 + n*16 + fr;
        const float bb = bias[col];
        #pragma unroll
        for (int mi = 0; mi < 4; ++mi){
            const int row = m0 + wr*64 + mi*16 + fq*4;
            #pragma unroll
            for (int r = 0; r < 4; ++r)
                out[(size_t)(row + r) * D_OUT + col] = acc[mi][n][r] + bb;
        }
    }
}

// ---------------------------------------------------------------------------
extern "C" void kernel_launch(void* const* d_in, const int* in_sizes, int n_in,
                              void* d_out, int out_size, void* d_ws, size_t ws_size,
                              hipStream_t stream)
{
    const float* x      = (const float*)d_in[0];
    const float* w_base = (const float*)d_in[1];
    const float* b_base = (const float*)d_in[2];
    const float* wr_img = (const float*)d_in[3];
    const float* br_img = (const float*)d_in[4];
    const float* wr_txt = (const float*)d_in[5];
    const float* br_txt = (const float*)d_in[6];
    const float* lA     = (const float*)d_in[7];
    const float* lB     = (const float*)d_in[8];
    float* out = (float*)d_out;

    char* ws = (char*)d_ws;
    float*    c_ws = (float*)ws;                                    // 2 MB
    _Float16* xh   = (_Float16*)(ws + (size_t)(2<<20));             // 64 MB
    _Float16* wh   = (_Float16*)(ws + (size_t)(2<<20) + 67108864);  // 32 MB
    _Float16* wl   = (_Float16*)(ws + (size_t)(2<<20) + 100663296); // 32 MB

    convert_kernel<<<dim3(24576), dim3(256), 0, stream>>>(x, w_base, xh, wh, wl);
    lora_c_kernel<<<dim3(NTOK/32), dim3(256), 0, stream>>>(
        x, wr_img, br_img, wr_txt, br_txt, lA, c_ws);
    main_gemm_kernel<<<dim3(1024), dim3(512), 0, stream>>>(
        xh, wh, wl, b_base, lB, c_ws, out);
}

// Round 3
// 566.297 us; speedup vs baseline: 2.2678x; 1.4243x over previous
//
#include <hip/hip_runtime.h>
#include <hip/hip_bf16.h>

#define D_IN   4096
#define D_OUT  4096
#define NTOK   8192
#define SEQ    2048
#define ER     64

typedef float        f32x4  __attribute__((ext_vector_type(4)));
typedef unsigned int u32x4  __attribute__((ext_vector_type(4)));
typedef unsigned int u32x2  __attribute__((ext_vector_type(2)));
typedef short        s16x8  __attribute__((ext_vector_type(8)));
typedef __bf16       bf16x8 __attribute__((ext_vector_type(8)));
typedef _Float16     f16x8  __attribute__((ext_vector_type(8)));

// ---------------- bf16 helpers (lora path, numerics unchanged) --------------
__device__ inline unsigned f2bf1(float f){
    unsigned u = __builtin_bit_cast(unsigned, f);
    return (u + 0x7fffu + ((u >> 16) & 1u)) >> 16;
}
__device__ inline unsigned pack2(float a, float b){ return f2bf1(a) | (f2bf1(b) << 16); }
__device__ inline f32x4 mfma_bf16(s16x8 a, s16x8 b, f32x4 c){
    return __builtin_amdgcn_mfma_f32_16x16x32_bf16(
        __builtin_bit_cast(bf16x8, a), __builtin_bit_cast(bf16x8, b), c, 0, 0, 0);
}
__device__ inline f32x4 mfma16(s16x8 a, s16x8 b, f32x4 c){
    return __builtin_amdgcn_mfma_f32_16x16x32_f16(
        __builtin_bit_cast(f16x8, a), __builtin_bit_cast(f16x8, b), c, 0, 0, 0);
}

// ---------------------------------------------------------------------------
// K0: w f32 -> fp16 (single plane; single-product fp16 GEMM).
// ---------------------------------------------------------------------------
__global__ __launch_bounds__(256) void convert_w_kernel(
    const float* __restrict__ w, _Float16* __restrict__ wh)
{
    size_t i = ((size_t)blockIdx.x * 256 + threadIdx.x) * 8;
    f32x4 a = *(const f32x4*)(w + i);
    f32x4 c = *(const f32x4*)(w + i + 4);
    f16x8 h;
    #pragma unroll
    for (int j = 0; j < 4; ++j){ h[j] = (_Float16)a[j]; h[4+j] = (_Float16)c[j]; }
    *(f16x8*)(wh + i) = h;
}

// ---------------------------------------------------------------------------
// K1: fused router + LoRA-A projection + x->fp16 conversion.
// 16-token tiles (512 blocks -> 2 blocks/CU), K-chunk 128, 32 iterations.
// ---------------------------------------------------------------------------
__global__ __launch_bounds__(256) void lora_c_kernel(
    const float* __restrict__ x,
    const float* __restrict__ wr_img, const float* __restrict__ br_img,
    const float* __restrict__ wr_txt, const float* __restrict__ br_txt,
    const float* __restrict__ lA,
    _Float16* __restrict__ xh, float* __restrict__ c_ws)
{
    __shared__ short xs[16][136];
    __shared__ short bs[80][136];
    __shared__ float lg[16][4];

    const int tid  = threadIdx.x;
    const int lane = tid & 63;
    const int wid  = tid >> 6;
    const int t0   = blockIdx.x * 16;
    const bool img = ((t0 % SEQ) < 32);
    const float* wrr = img ? wr_img : wr_txt;
    const float* br  = img ? br_img : br_txt;

    // zero router pad rows 68..79
    for (int idx = tid; idx < 816; idx += 256)
        ((unsigned*)&bs[68][0])[idx] = 0u;

    const int xr  = tid >> 4;           // 0..15
    const int xc8 = (tid & 15) * 8;     // 0..120
    const int lr  = tid >> 2;           // 0..63
    const int lc  = (tid & 3) * 4;
    const int rrow = tid >> 5;          // valid tid<128 -> 0..3
    const int rcol = (tid & 31) * 4;

    f32x4 rx0, rx1, rb[8], rv = {0.f,0.f,0.f,0.f};
    rx0 = *(const f32x4*)(x + (size_t)(t0 + xr) * D_IN + xc8);
    rx1 = *(const f32x4*)(x + (size_t)(t0 + xr) * D_IN + xc8 + 4);
    #pragma unroll
    for (int j = 0; j < 8; ++j) rb[j] = *(const f32x4*)(lA + (size_t)lr * D_IN + lc + j*16);
    if (tid < 128) rv = *(const f32x4*)(wrr + (size_t)rrow * D_IN + rcol);

    f32x4 acc0 = {0,0,0,0}, accR0 = {0,0,0,0};
    const int fr = lane & 15, fq = lane >> 4;

    for (int ks = 0; ks < 32; ++ks){
        __syncthreads();
        *(u32x4*)&xs[xr][xc8] = (u32x4){pack2(rx0[0],rx0[1]), pack2(rx0[2],rx0[3]),
                                        pack2(rx1[0],rx1[1]), pack2(rx1[2],rx1[3])};
        #pragma unroll
        for (int j = 0; j < 8; ++j)
            *(u32x2*)&bs[lr][lc + j*16] = (u32x2){pack2(rb[j][0],rb[j][1]), pack2(rb[j][2],rb[j][3])};
        if (tid < 128)
            *(u32x2*)&bs[64 + rrow][rcol] = (u32x2){pack2(rv[0],rv[1]), pack2(rv[2],rv[3])};
        __syncthreads();
        // fused x -> fp16 writeback (uses current rx regs)
        {
            f16x8 h;
            #pragma unroll
            for (int j = 0; j < 4; ++j){ h[j] = (_Float16)rx0[j]; h[4+j] = (_Float16)rx1[j]; }
            *(f16x8*)(xh + (size_t)(t0 + xr) * D_IN + ks*128 + xc8) = h;
        }
        if (ks < 31){
            const int ko = (ks + 1) * 128;
            rx0 = *(const f32x4*)(x + (size_t)(t0 + xr) * D_IN + ko + xc8);
            rx1 = *(const f32x4*)(x + (size_t)(t0 + xr) * D_IN + ko + xc8 + 4);
            #pragma unroll
            for (int j = 0; j < 8; ++j) rb[j] = *(const f32x4*)(lA + (size_t)lr * D_IN + ko + lc + j*16);
            if (tid < 128) rv = *(const f32x4*)(wrr + (size_t)rrow * D_IN + ko + rcol);
        }
        #pragma unroll
        for (int kc = 0; kc < 4; ++kc){
            s16x8 a0 = *(const s16x8*)&xs[fr][kc*32 + fq*8];
            s16x8 b0 = *(const s16x8*)&bs[wid*16 + fr][kc*32 + fq*8];
            acc0 = mfma_bf16(a0, b0, acc0);
            if (wid == 0){
                s16x8 bR = *(const s16x8*)&bs[64 + fr][kc*32 + fq*8];
                accR0 = mfma_bf16(a0, bR, accR0);
            }
        }
    }

    __syncthreads();
    if (wid == 0 && fr < 4){
        #pragma unroll
        for (int r = 0; r < 4; ++r)
            lg[fq*4 + r][fr] = accR0[r] + br[fr];
    }
    __syncthreads();
    if (tid < 16){
        float l0 = lg[tid][0], l1 = lg[tid][1], l2 = lg[tid][2], l3 = lg[tid][3];
        float mx = fmaxf(fmaxf(l0, l1), fmaxf(l2, l3));
        float e0 = expf(l0 - mx), e1 = expf(l1 - mx), e2 = expf(l2 - mx), e3 = expf(l3 - mx);
        float inv = 2.0f / (e0 + e1 + e2 + e3);
        lg[tid][0] = e0 * inv; lg[tid][1] = e1 * inv;
        lg[tid][2] = e2 * inv; lg[tid][3] = e3 * inv;
    }
    __syncthreads();
    #pragma unroll
    for (int r = 0; r < 4; ++r){
        const int row0 = fq*4 + r;
        c_ws[(size_t)(t0 + row0) * ER + wid*16 + fr] = acc0[r] * lg[row0][wid];
    }
}

// ---------------------------------------------------------------------------
// K2: main GEMM, m201-exact geometry: BM=BN=256, BK=64, 8 waves (2Mx4N),
// wave tile 128x64, fp16 single product, 128 KiB LDS double-buffer,
// quadrant-rotation phases (0-12 ds_reads/phase, <=64 operand VGPRs live).
// Epilogue: LoRA second projection (c @ Bt via MFMA, K=64) + bias.
// ---------------------------------------------------------------------------
#define REG_A0 0
#define REG_A1 16384
#define REG_B0 32768
#define REG_B1 49152
#define BUFSZ  65536

__device__ inline void gload16(const void* g, void* l){
    __builtin_amdgcn_global_load_lds(
        (const __attribute__((address_space(1))) unsigned*)g,
        (__attribute__((address_space(3))) unsigned*)l, 16, 0, 0);
}
// half-tile = 128 rows x 64 fp16; q = j*512+tid; row=q>>3, chunk XOR-swizzled
__device__ inline void stage_half_tile(const _Float16* gbase, char* lds, int tid){
    #pragma unroll
    for (int j = 0; j < 2; ++j){
        int q   = j*512 + tid;
        int row = q >> 3;
        int c7  = (q & 7) ^ (row & 7);
        gload16(gbase + (size_t)row * D_IN + c7*8, lds + q*16);
    }
}
__device__ inline s16x8 ldsfrag(const char* region, int row, int kc, int fq){
    int ch = ((kc << 2) + fq) ^ (row & 7);
    return *(const s16x8*)(region + row*128 + ch*16);
}
#define BAR()   __builtin_amdgcn_s_barrier()
#define LGKM0() asm volatile("s_waitcnt lgkmcnt(0)" ::: "memory")
#define PRIO(x) __builtin_amdgcn_s_setprio(x)

__global__ __launch_bounds__(512, 2) void main_gemm_kernel(
    const _Float16* __restrict__ xh, const _Float16* __restrict__ wh,
    const float* __restrict__ bias, const float* __restrict__ lB,
    const float* __restrict__ c_ws, float* __restrict__ out)
{
    __shared__ __align__(16) char smem[2 * BUFSZ];

    const int tid  = threadIdx.x;
    const int lane = tid & 63;
    const int wid  = tid >> 6;
    const int wr   = wid >> 2;           // 0..1  (row half)
    const int wc   = wid & 3;            // 0..3  (64-col strip)
    const int fr   = lane & 15, fq = lane >> 4;

    const int bid = blockIdx.x;                      // 512 blocks: 32 mt x 16 nt
    const int swz = (bid & 7) * 64 + (bid >> 3);     // XCD swizzle (512 % 8 == 0)
    const int mt  = swz & 31, nt = swz >> 5;
    const int m0  = mt * 256, n0 = nt * 256;

    const _Float16* gA0 = xh + (size_t)m0 * D_IN;
    const _Float16* gA1 = gA0 + (size_t)128 * D_IN;
    const _Float16* gB0 = wh + (size_t)n0 * D_IN;
    const _Float16* gB1 = gB0 + (size_t)128 * D_IN;

    // prologue: tile0 full (8 loads), tile1 {B0,A0,A1} (6 loads)
    stage_half_tile(gA0,      smem + REG_A0,         tid);
    stage_half_tile(gA1,      smem + REG_A1,         tid);
    stage_half_tile(gB0,      smem + REG_B0,         tid);
    stage_half_tile(gB1,      smem + REG_B1,         tid);
    stage_half_tile(gB0 + 64, smem + BUFSZ + REG_B0, tid);
    stage_half_tile(gA0 + 64, smem + BUFSZ + REG_A0, tid);
    stage_half_tile(gA1 + 64, smem + BUFSZ + REG_A1, tid);
    asm volatile("s_waitcnt vmcnt(6)" ::: "memory");
    BAR();

    f32x4 acc[8][4];
    #pragma unroll
    for (int mi = 0; mi < 8; ++mi)
        #pragma unroll
        for (int n = 0; n < 4; ++n) acc[mi][n] = (f32x4){0.f,0.f,0.f,0.f};

    const int bcol0 = (wc & 1) * 64;

    for (int it = 0; it < 32; ++it){
        const bool pred = (it < 31);
        #pragma unroll
        for (int hf = 0; hf < 2; ++hf){
            char* buf  = smem + hf * BUFSZ;          // tile 2it+hf
            char* obuf = smem + (hf ^ 1) * BUFSZ;
            const char* Ab = buf + wr * 16384;                     // A0/A1 region
            const char* Bb = buf + REG_B0 + (wc >> 1) * 16384;     // B0/B1 region
            const size_t kP0 = (size_t)(2*it + 1 + hf) * 64;       // P0-staged tile
            const size_t kN  = (size_t)(2*it + 2 + hf) * 64;       // P2/P3-staged tile
            const bool  prP0 = (hf == 0) ? true : pred;

            s16x8 af[4][2], blo[2][2], bhi[2][2];
            // ---- P0: quadrant (Alo, Blo); reads 12; stage other-buf B1
            #pragma unroll
            for (int mi = 0; mi < 4; ++mi)
                #pragma unroll
                for (int kc = 0; kc < 2; ++kc)
                    af[mi][kc] = ldsfrag(Ab, mi*16 + fr, kc, fq);
            #pragma unroll
            for (int nn = 0; nn < 2; ++nn)
                #pragma unroll
                for (int kc = 0; kc < 2; ++kc)
                    blo[nn][kc] = ldsfrag(Bb, bcol0 + nn*16 + fr, kc, fq);
            if (prP0) stage_half_tile(gB1 + kP0, obuf + REG_B1, tid);
            BAR(); LGKM0(); PRIO(1);
            #pragma unroll
            for (int mi = 0; mi < 4; ++mi)
                #pragma unroll
                for (int nn = 0; nn < 2; ++nn)
                    #pragma unroll
                    for (int kc = 0; kc < 2; ++kc)
                        acc[mi][nn] = mfma16(af[mi][kc], blo[nn][kc], acc[mi][nn]);
            PRIO(0); BAR();
            // ---- P1: quadrant (Alo, Bhi); reads 4
            #pragma unroll
            for (int nn = 0; nn < 2; ++nn)
                #pragma unroll
                for (int kc = 0; kc < 2; ++kc)
                    bhi[nn][kc] = ldsfrag(Bb, bcol0 + 32 + nn*16 + fr, kc, fq);
            BAR(); LGKM0(); PRIO(1);
            #pragma unroll
            for (int mi = 0; mi < 4; ++mi)
                #pragma unroll
                for (int nn = 0; nn < 2; ++nn)
                    #pragma unroll
                    for (int kc = 0; kc < 2; ++kc)
                        acc[mi][2+nn] = mfma16(af[mi][kc], bhi[nn][kc], acc[mi][2+nn]);
            PRIO(0); BAR();
            // ---- P2: quadrant (Ahi, Bhi); reads 8; stage cur-buf B0 (B reads done)
            #pragma unroll
            for (int mi = 0; mi < 4; ++mi)
                #pragma unroll
                for (int kc = 0; kc < 2; ++kc)
                    af[mi][kc] = ldsfrag(Ab, 64 + mi*16 + fr, kc, fq);
            if (pred) stage_half_tile(gB0 + kN, buf + REG_B0, tid);
            BAR(); LGKM0(); PRIO(1);
            #pragma unroll
            for (int mi = 0; mi < 4; ++mi)
                #pragma unroll
                for (int nn = 0; nn < 2; ++nn)
                    #pragma unroll
                    for (int kc = 0; kc < 2; ++kc)
                        acc[4+mi][2+nn] = mfma16(af[mi][kc], bhi[nn][kc], acc[4+mi][2+nn]);
            PRIO(0); BAR();
            // ---- P3: quadrant (Ahi, Blo); reads 0; stage cur-buf A0+A1 (A reads done)
            if (pred){
                stage_half_tile(gA0 + kN, buf + REG_A0, tid);
                stage_half_tile(gA1 + kN, buf + REG_A1, tid);
            }
            BAR(); PRIO(1);
            #pragma unroll
            for (int mi = 0; mi < 4; ++mi)
                #pragma unroll
                for (int nn = 0; nn < 2; ++nn)
                    #pragma unroll
                    for (int kc = 0; kc < 2; ++kc)
                        acc[4+mi][nn] = mfma16(af[mi][kc], blo[nn][kc], acc[4+mi][nn]);
            PRIO(0);
            if (pred)           asm volatile("s_waitcnt vmcnt(6)" ::: "memory");
            else if (hf == 0)   asm volatile("s_waitcnt vmcnt(0)" ::: "memory");
            BAR();
        }
    }

    // ---- epilogue: stage c[256][64] fp16 @0, Bt[256][64] fp16 @32K ---------
    #pragma unroll
    for (int k2 = 0; k2 < 4; ++k2){
        int q = tid + k2*512;              // 0..2047
        int row = q >> 3, cc = q & 7;
        const float* cs = c_ws + (size_t)(m0 + row) * ER + cc*8;
        f32x4 v0 = *(const f32x4*)cs;
        f32x4 v1 = *(const f32x4*)(cs + 4);
        f16x8 h;
        #pragma unroll
        for (int j = 0; j < 4; ++j){ h[j] = (_Float16)v0[j]; h[4+j] = (_Float16)v1[j]; }
        *(s16x8*)(smem + row*128 + (cc ^ (row & 7))*16) = __builtin_bit_cast(s16x8, h);
    }
    #pragma unroll
    for (int k2 = 0; k2 < 4; ++k2){
        int q = tid + k2*512;              // 0..2047
        int row = q >> 3, cc = q & 7;
        int e = cc >> 1, r0 = (cc & 1) * 8;
        const float* bsrc = lB + (size_t)e * D_OUT * 16 + (size_t)(n0 + row) * 16 + r0;
        f32x4 v0 = *(const f32x4*)bsrc;
        f32x4 v1 = *(const f32x4*)(bsrc + 4);
        f16x8 h;
        #pragma unroll
        for (int j = 0; j < 4; ++j){ h[j] = (_Float16)v0[j]; h[4+j] = (_Float16)v1[j]; }
        *(s16x8*)(smem + 32768 + row*128 + (cc ^ (row & 7))*16) = __builtin_bit_cast(s16x8, h);
    }
    __syncthreads();

    #pragma unroll
    for (int kc = 0; kc < 2; ++kc){
        s16x8 btf[4];
        #pragma unroll
        for (int n = 0; n < 4; ++n)
            btf[n] = ldsfrag(smem + 32768, wc*64 + n*16 + fr, kc, fq);
        #pragma unroll
        for (int mi = 0; mi < 8; ++mi){
            s16x8 cf = ldsfrag(smem, wr*128 + mi*16 + fr, kc, fq);
            #pragma unroll
            for (int n = 0; n < 4; ++n)
                acc[mi][n] = mfma16(cf, btf[n], acc[mi][n]);
        }
    }

    #pragma unroll
    for (int n = 0; n < 4; ++n){
        const int col = n0 + wc*64 + n*16 + fr;
        const float bb = bias[col];
        #pragma unroll
        for (int mi = 0; mi < 8; ++mi){
            const int row = m0 + wr*128 + mi*16 + fq*4;
            #pragma unroll
            for (int r = 0; r < 4; ++r)
                out[(size_t)(row + r) * D_OUT + col] = acc[mi][n][r] + bb;
        }
    }
}

// ---------------------------------------------------------------------------
extern "C" void kernel_launch(void* const* d_in, const int* in_sizes, int n_in,
                              void* d_out, int out_size, void* d_ws, size_t ws_size,
                              hipStream_t stream)
{
    const float* x      = (const float*)d_in[0];
    const float* w_base = (const float*)d_in[1];
    const float* b_base = (const float*)d_in[2];
    const float* wr_img = (const float*)d_in[3];
    const float* br_img = (const float*)d_in[4];
    const float* wr_txt = (const float*)d_in[5];
    const float* br_txt = (const float*)d_in[6];
    const float* lA     = (const float*)d_in[7];
    const float* lB     = (const float*)d_in[8];
    float* out = (float*)d_out;

    char* ws = (char*)d_ws;
    float*    c_ws = (float*)ws;                          // 2 MB
    _Float16* xh   = (_Float16*)(ws + (size_t)(2<<20));   // 64 MB
    _Float16* wh   = (_Float16*)(ws + (size_t)(66<<20));  // 32 MB

    convert_w_kernel<<<dim3(8192), dim3(256), 0, stream>>>(w_base, wh);
    lora_c_kernel<<<dim3(NTOK/16), dim3(256), 0, stream>>>(
        x, wr_img, br_img, wr_txt, br_txt, lA, xh, c_ws);
    main_gemm_kernel<<<dim3(512), dim3(512), 0, stream>>>(
        xh, wh, b_base, lB, c_ws, out);
}